// Round 1
// baseline (576.323 us; speedup 1.0000x reference)
//
#include <hip/hip_runtime.h>
#include <hip/hip_bf16.h>

// VGAE: 2x SAGE-mean conv layers (128->32->32 {mu, logstd}), reparameterize,
// then dense dot-product decode adj = sigmoid(z z^T) [10000 x 10000].
//
// N=10000, E=320000, F_IN=128, HID=32. All fp32 (no fp32 MFMA on CDNA4;
// decoder is HBM-write-bound anyway: 400MB output).
//
// Trick: mean-aggregation is linear, so project first (x @ W_neigh, 32 dims)
// and aggregate the 32-dim projections over edges -> 4x less edge traffic.

#define N_NODES 10000
#define N_EDGES 320000
#define F_IN 128
#define HID 32

// ---------------- Layer-1 input GEMM: xws = x@W1s + b1, xwn = x@W1n -------
__global__ __launch_bounds__(256) void k_gemm_in(
    const float* __restrict__ x, const float* __restrict__ Ws,
    const float* __restrict__ Wn, const float* __restrict__ b,
    float* __restrict__ outS, float* __restrict__ outN) {
  __shared__ float sWs[F_IN * HID];   // 16 KB
  __shared__ float sWn[F_IN * HID];   // 16 KB
  __shared__ float sx[8 * F_IN];      // 4 KB
  const int t = threadIdx.x;
  for (int i = t * 4; i < F_IN * HID; i += 1024) {
    *(float4*)&sWs[i] = *(const float4*)&Ws[i];
    *(float4*)&sWn[i] = *(const float4*)&Wn[i];
  }
  const int row0 = blockIdx.x * 8;
  {
    // 8 rows x 128 = 1024 floats; one float4 per thread
    const int i = t * 4;
    const int r = i >> 7, k = i & 127;
    const int gr = row0 + r;
    float4 v = make_float4(0.f, 0.f, 0.f, 0.f);
    if (gr < N_NODES) v = *(const float4*)&x[gr * F_IN + k];
    *(float4*)&sx[i] = v;
  }
  __syncthreads();
  const int r = t >> 5, c = t & 31;
  const int grow = row0 + r;
  float accS = 0.f, accN = 0.f;
  #pragma unroll 8
  for (int k = 0; k < F_IN; ++k) {
    const float a = sx[r * F_IN + k];
    accS += a * sWs[k * HID + c];
    accN += a * sWn[k * HID + c];
  }
  if (grow < N_NODES) {
    outS[grow * HID + c] = accS + b[c];
    outN[grow * HID + c] = accN;
  }
}

// ---------------- Edge aggregation: agg[dst] += feat[src]  ----------------
// One thread per (edge, feature). Optionally also counts degree (k==0 lane).
__global__ __launch_bounds__(256) void k_aggregate(
    const float* __restrict__ feat, const int* __restrict__ src,
    const int* __restrict__ dst, float* __restrict__ agg,
    float* __restrict__ deg) {
  const int tid = blockIdx.x * 256 + threadIdx.x;
  const int e = tid >> 5;
  const int k = tid & 31;
  if (e >= N_EDGES) return;
  const int s = src[e];
  const int d = dst[e];
  atomicAdd(&agg[d * HID + k], feat[s * HID + k]);
  if (deg != nullptr && k == 0) atomicAdd(&deg[d], 1.0f);
}

// ---------------- Layer-1 finish: h = relu(xws + agg/deg) -----------------
__global__ __launch_bounds__(256) void k_layer1_finish(
    const float* __restrict__ xws, const float* __restrict__ agg,
    const float* __restrict__ deg, float* __restrict__ h) {
  const int i = blockIdx.x * 256 + threadIdx.x;
  if (i >= N_NODES * HID) return;
  const int node = i >> 5;
  float dv = deg[node];
  dv = dv > 1.f ? dv : 1.f;
  const float v = xws[i] + agg[i] / dv;
  h[i] = v > 0.f ? v : 0.f;
}

// ---------------- Layer 2 (mu & logstd) + reparameterize ------------------
// mu = h@Wms + hn@Wmn + bm ; ls = h@Wls + hn@Wln + bl ; z = mu + eps*exp(ls)
__global__ __launch_bounds__(256) void k_layer2(
    const float* __restrict__ h, const float* __restrict__ aggh,
    const float* __restrict__ deg, const float* __restrict__ eps,
    const float* __restrict__ Wms, const float* __restrict__ Wmn,
    const float* __restrict__ bm, const float* __restrict__ Wls,
    const float* __restrict__ Wln, const float* __restrict__ bl,
    float* __restrict__ mu_out, float* __restrict__ ls_out,
    float* __restrict__ z) {
  __shared__ float sMs[HID * HID], sMn[HID * HID];
  __shared__ float sLs[HID * HID], sLn[HID * HID];
  __shared__ float sh[8 * HID], shn[8 * HID];
  const int t = threadIdx.x;
  {
    const int i = t * 4;  // 1024 floats per matrix, one float4 per thread
    *(float4*)&sMs[i] = *(const float4*)&Wms[i];
    *(float4*)&sMn[i] = *(const float4*)&Wmn[i];
    *(float4*)&sLs[i] = *(const float4*)&Wls[i];
    *(float4*)&sLn[i] = *(const float4*)&Wln[i];
  }
  const int node0 = blockIdx.x * 8;
  const int lr = t >> 5;         // 0..7
  const int gnode_ld = node0 + lr;
  if (gnode_ld < N_NODES) {
    float dv = deg[gnode_ld];
    dv = dv > 1.f ? dv : 1.f;
    sh[t] = h[node0 * HID + t];
    shn[t] = aggh[node0 * HID + t] / dv;
  } else {
    sh[t] = 0.f;
    shn[t] = 0.f;
  }
  __syncthreads();
  const int r = t >> 5, c = t & 31;
  const int node = node0 + r;
  float mu = 0.f, ls = 0.f;
  #pragma unroll 8
  for (int k = 0; k < HID; ++k) {
    const float a = sh[r * HID + k];
    const float an = shn[r * HID + k];
    mu += a * sMs[k * HID + c] + an * sMn[k * HID + c];
    ls += a * sLs[k * HID + c] + an * sLn[k * HID + c];
  }
  if (node < N_NODES) {
    mu += bm[c];
    ls += bl[c];
    const int idx = node * HID + c;
    mu_out[idx] = mu;
    ls_out[idx] = ls;
    z[idx] = mu + eps[idx] * __expf(ls);
  }
}

// ---------------- Decoder: adj = sigmoid(z z^T) ---------------------------
// 128x128 tile per 256-thread block; each thread 8x8 outputs; K=32 via LDS.
// LDS rows padded to 36 floats (144 B, 16B-aligned; bank = (4c+k)%32 -> at
// most 2-way conflict on the b-reads, which is free).
__global__ __launch_bounds__(256) void k_decode(const float* __restrict__ z,
                                                float* __restrict__ adj) {
  __shared__ float za[128][36];
  __shared__ float zb[128][36];
  const int r0 = blockIdx.y * 128;
  const int c0 = blockIdx.x * 128;
  const int t = threadIdx.x;
  // stage 128 rows x 32 floats for both tile-row block and tile-col block
  for (int i = t; i < 128 * 8; i += 256) {
    const int row = i >> 3, k0 = (i & 7) << 2;
    const int gr = r0 + row;
    const int gc = c0 + row;
    float4 va = make_float4(0.f, 0.f, 0.f, 0.f);
    float4 vb = make_float4(0.f, 0.f, 0.f, 0.f);
    if (gr < N_NODES) va = *(const float4*)&z[gr * HID + k0];
    if (gc < N_NODES) vb = *(const float4*)&z[gc * HID + k0];
    *(float4*)&za[row][k0] = va;
    *(float4*)&zb[row][k0] = vb;
  }
  __syncthreads();
  const int tx = t & 15, ty = t >> 4;
  float acc[8][8];
  #pragma unroll
  for (int i = 0; i < 8; ++i)
    #pragma unroll
    for (int j = 0; j < 8; ++j) acc[i][j] = 0.f;

  #pragma unroll 4
  for (int k = 0; k < HID; ++k) {
    float a[8], b[8];
    #pragma unroll
    for (int i = 0; i < 8; ++i) a[i] = za[ty + i * 16][k];
    #pragma unroll
    for (int j = 0; j < 8; ++j) b[j] = zb[tx + j * 16][k];
    #pragma unroll
    for (int i = 0; i < 8; ++i)
      #pragma unroll
      for (int j = 0; j < 8; ++j) acc[i][j] += a[i] * b[j];
  }

  #pragma unroll
  for (int i = 0; i < 8; ++i) {
    const int r = r0 + ty + i * 16;
    if (r >= N_NODES) continue;
    float* rowp = adj + (size_t)r * N_NODES;
    #pragma unroll
    for (int j = 0; j < 8; ++j) {
      const int c = c0 + tx + j * 16;
      if (c < N_NODES) {
        const float v = acc[i][j];
        rowp[c] = __builtin_amdgcn_rcpf(1.f + __expf(-v));
      }
    }
  }
}

extern "C" void kernel_launch(void* const* d_in, const int* in_sizes, int n_in,
                              void* d_out, int out_size, void* d_ws,
                              size_t ws_size, hipStream_t stream) {
  const float* x   = (const float*)d_in[0];
  const int* src   = (const int*)d_in[1];
  const int* dst   = (const int*)d_in[2];
  const float* eps = (const float*)d_in[3];
  const float* W1s = (const float*)d_in[4];
  const float* W1n = (const float*)d_in[5];
  const float* b1  = (const float*)d_in[6];
  const float* Wms = (const float*)d_in[7];
  const float* Wmn = (const float*)d_in[8];
  const float* bm  = (const float*)d_in[9];
  const float* Wls = (const float*)d_in[10];
  const float* Wln = (const float*)d_in[11];
  const float* bl  = (const float*)d_in[12];

  float* out = (float*)d_out;
  float* adj = out;                                      // [N, N]
  float* mu_out = out + (size_t)N_NODES * N_NODES;       // [N, HID]
  float* ls_out = mu_out + (size_t)N_NODES * HID;        // [N, HID]

  // workspace layout (floats). zero-initialized region first (deg+agg+aggh).
  float* ws = (float*)d_ws;
  float* deg  = ws;                       // N
  float* agg  = ws + N_NODES;             // N*HID
  float* aggh = agg + N_NODES * HID;      // N*HID
  float* xws  = aggh + N_NODES * HID;     // N*HID
  float* xwn  = xws + N_NODES * HID;      // N*HID
  float* h    = xwn + N_NODES * HID;      // N*HID
  float* z    = h + N_NODES * HID;        // N*HID
  (void)ws_size; (void)in_sizes; (void)n_in; (void)out_size;

  // zero deg + agg + aggh (contiguous): (N + 2*N*HID) floats
  hipMemsetAsync(ws, 0, (size_t)(N_NODES + 2 * N_NODES * HID) * sizeof(float),
                 stream);

  // Layer-1 projections
  k_gemm_in<<<dim3((N_NODES + 7) / 8), dim3(256), 0, stream>>>(x, W1s, W1n, b1,
                                                               xws, xwn);
  // aggregate projected neighbors + degree
  k_aggregate<<<dim3((N_EDGES * HID) / 256), dim3(256), 0, stream>>>(
      xwn, src, dst, agg, deg);
  // h = relu(xws + agg/deg)
  k_layer1_finish<<<dim3((N_NODES * HID) / 256), dim3(256), 0, stream>>>(
      xws, agg, deg, h);
  // aggregate h
  k_aggregate<<<dim3((N_EDGES * HID) / 256), dim3(256), 0, stream>>>(
      h, src, dst, aggh, nullptr);
  // layer 2 + reparameterize
  k_layer2<<<dim3((N_NODES + 7) / 8), dim3(256), 0, stream>>>(
      h, aggh, deg, eps, Wms, Wmn, bm, Wls, Wln, bl, mu_out, ls_out, z);
  // decode
  dim3 dgrid((N_NODES + 127) / 128, (N_NODES + 127) / 128);
  k_decode<<<dgrid, dim3(256), 0, stream>>>(z, adj);
}